// Round 6
// baseline (27892.484 us; speedup 1.0000x reference)
//
#include <hip/hip_runtime.h>
#include <hip/hip_bf16.h>

#define TSTEPS 4096
#define XD 256
#define HD 2048
#define YD 256
#define KD 2304   // XD + HD
#define NWG 256
#define NT 512

// ---- LDS layout (bytes) ----
#define WU_OFF 0
#define WR_OFF (8*KD*2)            // 36864
#define WC_OFF (16*KD*2)           // 73728
#define WY_OFF (24*KD*2)           // 110592
#define V1_OFF (WY_OFF + HD*4)     // 118784  v1 = [x_t | h_{t-1}]
#define V2_OFF (V1_OFF + KD*4)     // 128000  v2 = [x_t | r]
#define RED_OFF (V2_OFF + KD*4)    // 137216  red: u[8], yp[8], bu[8], br[8], bc[8], by
#define LDS_BYTES (RED_OFF + 256)  // 137472

// ---- workspace layout ----
// go lines first (zeroed), then 4 sentinel-armed exchange buffers (0x7F).
// |h|<=1, |r|<=1 provably (tanh/sigmoid bounds, h0=0) -> 0x7F7F7F7F (3.4e38)
// is unreachable -> safe sentinel, byte-settable via memset(0x7F).
#define GO_BYTES  1024             // 8 go lines x 128B
#define HB0_OFF   (GO_BYTES)
#define HB1_OFF   (GO_BYTES + 8192)
#define RB0_OFF   (GO_BYTES + 16384)
#define RB1_OFF   (GO_BYTES + 24576)
#define BUF_BYTES 32768
#define SENT32 0x7F7F7F7Fu

__device__ __forceinline__ float bflo(unsigned u){ return __uint_as_float(u << 16); }
__device__ __forceinline__ float bfhi(unsigned u){ return __uint_as_float(u & 0xffff0000u); }
__device__ __forceinline__ unsigned short f2bf(float f){
  unsigned b = __float_as_uint(f);
  b += 0x7fffu + ((b >> 16) & 1u);   // RTNE (inputs finite)
  return (unsigned short)(b >> 16);
}
__device__ __forceinline__ float sigmoidf_(float x){ return 1.0f / (1.0f + __expf(-x)); }

__device__ __forceinline__ void gst32f(float* p, float v){
  __hip_atomic_store(p, v, __ATOMIC_RELAXED, __HIP_MEMORY_SCOPE_AGENT);
}

// AGENT-scope coalesced 16B load (sc1 only — LLC-serviced; R2/R3-proven
// coherence semantics, 4 lanes per 128B line).
__device__ __forceinline__ float4 cohload16(const float4* p){
  float4 r;
  asm volatile("global_load_dwordx4 %0, %1, off sc1\n\t"
               "s_waitcnt vmcnt(0)"
               : "=v"(r) : "v"(p) : "memory");
  return r;
}

__device__ __forceinline__ int has_sent(float4 v){
  return (__float_as_uint(v.x) == SENT32) | (__float_as_uint(v.y) == SENT32) |
         (__float_as_uint(v.z) == SENT32) | (__float_as_uint(v.w) == SENT32);
}

// Relay exchange with single-shot speculative gather.
//  - every thread issues ONE speculative 16B read of its slice (data flips
//    sentinel->value exactly once, so a non-sentinel spec read is final)
//  - WG0: per-thread poll-gather (512 pollers grid-wide) doubles as the
//    readiness detector; then broadcasts epoch to 8 go lines
//  - other WGs: tid0 spins on go (255 pollers); after syncthreads, only
//    sentinel slices reload once (certified ready)
// Minimal-poller property of R2's relay preserved; one less leg (no flags),
// gather RTT overlapped with the go-wait.
__device__ __forceinline__ void relay_gather(const float* gbuf, float* ldsdst, unsigned* go,
                                             unsigned epoch, int wg, int tid, long* budget){
  const float4* p = (const float4*)gbuf + tid;
  float4 v = cohload16(p);                    // speculative single-shot
  if (wg == 0) {
    while (has_sent(v)) {
      if (--(*budget) < 0) break;             // anti-hang
      __builtin_amdgcn_s_sleep(2);
      v = cohload16(p);
    }
    ((float4*)ldsdst)[tid] = v;
    __syncthreads();                          // all slices seen at LLC
    if (tid < 8)
      __hip_atomic_store(go + 32*tid, epoch, __ATOMIC_RELAXED, __HIP_MEMORY_SCOPE_AGENT);
  } else {
    if (tid == 0) {
      unsigned* g = go + 32*(wg & 7);
      while (__hip_atomic_load(g, __ATOMIC_RELAXED, __HIP_MEMORY_SCOPE_AGENT) < epoch) {
        if (--(*budget) < 0) break;
        __builtin_amdgcn_s_sleep(1);
      }
    }
    __syncthreads();
    if (has_sent(v)) v = cohload16(p);        // laggard fix-up: one reload
    ((float4*)ldsdst)[tid] = v;
  }
}

// Re-arm my 8-float slice (32B) of a consumed exchange buffer with sentinel.
__device__ __forceinline__ void reset_slice(float* gbuf, int col0, int tid){
  if (tid < 2) {
    unsigned long long s = 0x7F7F7F7F7F7F7F7FULL;
    unsigned long long* p = (unsigned long long*)(gbuf + col0) + 2*tid;
    __hip_atomic_store(p,     s, __ATOMIC_RELAXED, __HIP_MEMORY_SCOPE_AGENT);
    __hip_atomic_store(p + 1, s, __ATOMIC_RELAXED, __HIP_MEMORY_SCOPE_AGENT);
  }
}

extern "C" __global__ void __launch_bounds__(NT)
gru_persistent(const float* __restrict__ x,  const float* __restrict__ h0,
               const float* __restrict__ Wc, const float* __restrict__ Wu,
               const float* __restrict__ Wr, const float* __restrict__ bc,
               const float* __restrict__ bu, const float* __restrict__ br,
               const float* __restrict__ Wy, const float* __restrict__ by,
               float* __restrict__ out, unsigned* wsu)
{
  extern __shared__ char smem[];
  unsigned short* wuS = (unsigned short*)(smem + WU_OFF);
  unsigned short* wrS = (unsigned short*)(smem + WR_OFF);
  unsigned short* wcS = (unsigned short*)(smem + WC_OFF);
  float* wyS = (float*)(smem + WY_OFF);
  float* v1  = (float*)(smem + V1_OFF);
  float* v2  = (float*)(smem + V2_OFF);
  float* red = (float*)(smem + RED_OFF);

  unsigned* go = wsu;   // 8 lines x 128B
  float* hb[2] = { (float*)((char*)wsu + HB0_OFF), (float*)((char*)wsu + HB1_OFF) };
  float* rb[2] = { (float*)((char*)wsu + RB0_OFF), (float*)((char*)wsu + RB1_OFF) };

  const int wg = blockIdx.x, tid = threadIdx.x;
  const int col0 = 8 * wg;

  // ---- one-time weight staging: WG j owns gate cols [8j,8j+8), y col j ----
  for (int idx = tid; idx < 8*KD; idx += NT) {
    int c = idx & 7, k = idx >> 3;
    size_t g = (size_t)k * HD + col0 + c;   // W is [KD, 2048] row-major
    wuS[c*KD + k] = f2bf(Wu[g]);
    wrS[c*KD + k] = f2bf(Wr[g]);
    wcS[c*KD + k] = f2bf(Wc[g]);
  }
  for (int k = tid; k < HD; k += NT) wyS[k] = Wy[(size_t)k * YD + wg];
  if (tid < 8) {
    red[16+tid] = bu[col0+tid];
    red[24+tid] = br[col0+tid];
    red[32+tid] = bc[col0+tid];
  }
  if (tid == 0) red[40] = by[wg];
  __syncthreads();

  long budget = 20000000;   // spin cap, then bail (no hang)

  // x_0 preload (register prefetch pipeline: xpref always holds x_t at step top)
  float4 xpref = make_float4(0.f, 0.f, 0.f, 0.f);
  if (tid < XD/4) xpref = ((const float4*)x)[tid];

  for (int t = 0; t < TSTEPS; ++t) {
    // x_t from prefetch registers (no HBM on the critical path)
    if (tid < XD/4) {
      ((float4*)v1)[tid] = xpref;
      ((float4*)v2)[tid] = xpref;
    }
    // h_{t-1} exchange (B2 of step t-1, epoch 2t)
    if (t == 0) {
      ((float4*)(v1 + XD))[tid] = ((const float4*)h0)[tid];
    } else {
      relay_gather(hb[(t+1)&1], v1 + XD, go, 2u*t, wg, tid, &budget);
    }
    __syncthreads();
    // h_{t-1} complete grid-wide => all WGs consumed r_{t-1} => safe to re-arm
    // my slice of rb[(t-1)&1] (next written at t+1, read at t+1 — ~full
    // exchange+phase gap before any speculative read can hit it).
    if (t) reset_slice(rb[(t+1)&1], col0, tid);

    // ---- phase 1: Lu (half-waves 0-7), Lr (half-waves 8-15); K = 2304 ----
    {
      int hw = tid >> 5, l = tid & 31, c = hw & 7;
      const unsigned short* wcol = ((hw < 8) ? wuS : wrS) + c * KD;
      float4 acc = make_float4(0.f, 0.f, 0.f, 0.f);
      #pragma unroll
      for (int i = 0; i < KD/128; ++i) {       // 18 iters, 4 MACs each
        int k = 4 * (l + 32 * i);
        float4 vv = *(const float4*)(v1 + k);
        uint2  wq = *(const uint2*)(wcol + k);
        acc.x = fmaf(vv.x, bflo(wq.x), acc.x);
        acc.y = fmaf(vv.y, bfhi(wq.x), acc.y);
        acc.z = fmaf(vv.z, bflo(wq.y), acc.z);
        acc.w = fmaf(vv.w, bfhi(wq.y), acc.w);
      }
      float s = (acc.x + acc.y) + (acc.z + acc.w);
      s += __shfl_xor(s, 16); s += __shfl_xor(s, 8); s += __shfl_xor(s, 4);
      s += __shfl_xor(s, 2);  s += __shfl_xor(s, 1);
      if (l == 0) {
        if (hw < 8) red[c] = sigmoidf_(s + red[16+c]);                              // u gate
        else gst32f(rb[t&1] + col0 + c, sigmoidf_(s + red[24+c]) * v1[XD+col0+c]);  // r*h
      }
    }

    // y[t-1] partials: needs only h_{t-1} (in v1) -> hidden under r-exchange.
    {
      int w = tid >> 6, l6 = tid & 63;
      int k = 256 * w + 4 * l6;
      float4 hv  = *(const float4*)(v1 + XD + k);
      float4 wy4 = *(const float4*)(wyS + k);
      float ys = fmaf(hv.x, wy4.x, fmaf(hv.y, wy4.y, fmaf(hv.z, wy4.z, hv.w * wy4.w)));
      ys += __shfl_xor(ys, 32); ys += __shfl_xor(ys, 16); ys += __shfl_xor(ys, 8);
      ys += __shfl_xor(ys, 4);  ys += __shfl_xor(ys, 2);  ys += __shfl_xor(ys, 1);
      if (l6 == 0) red[8 + w] = ys;
    }
    // x_{t+1} prefetch: issued here so its HBM latency overlaps the
    // r-exchange + phase 2 + h-exchange (registers live across the step).
    if (tid < XD/4 && t + 1 < TSTEPS)
      xpref = ((const float4*)(x + (size_t)(t+1) * XD))[tid];

    // r_t exchange (B1, epoch 2t+1)
    relay_gather(rb[t&1], v2 + XD, go, 2u*t + 1u, wg, tid, &budget);
    __syncthreads();
    // r_t complete grid-wide => all WGs consumed h_{t-1} => re-arm hb[(t-1)&1].
    if (t) reset_slice(hb[(t+1)&1], col0, tid);
    // y[t-1] store: fire-and-forget, overlaps phase 2.
    if (tid == 0 && t > 0) {
      float y = red[8]+red[9]+red[10]+red[11]+red[12]+red[13]+red[14]+red[15] + red[40];
      out[(size_t)(t-1) * YD + wg] = y;
    }

    // ---- phase 2: candidate c (wave w -> col w) ----
    {
      int w = tid >> 6, l6 = tid & 63;
      const unsigned short* ccol = wcS + w * KD;
      float4 acc = make_float4(0.f, 0.f, 0.f, 0.f);
      #pragma unroll
      for (int i = 0; i < KD/256; ++i) {       // 9 iters
        int k = 4 * (l6 + 64 * i);
        float4 vv = *(const float4*)(v2 + k);
        uint2  wq = *(const uint2*)(ccol + k);
        acc.x = fmaf(vv.x, bflo(wq.x), acc.x);
        acc.y = fmaf(vv.y, bfhi(wq.x), acc.y);
        acc.z = fmaf(vv.z, bflo(wq.y), acc.z);
        acc.w = fmaf(vv.w, bfhi(wq.y), acc.w);
      }
      float s = (acc.x + acc.y) + (acc.z + acc.w);
      s += __shfl_xor(s, 32); s += __shfl_xor(s, 16); s += __shfl_xor(s, 8);
      s += __shfl_xor(s, 4);  s += __shfl_xor(s, 2);  s += __shfl_xor(s, 1);

      if (l6 == 0) {
        float cc = tanhf(s + red[32 + w]);
        float u  = red[w];
        float hp = v1[XD + col0 + w];
        gst32f(hb[t&1] + col0 + w, cc * u + hp * (1.0f - u));   // h_t slice
      }
    }
    __syncthreads();
  }

  // ---- epilogue: y[T-1] and h_fin (final h exchange, epoch 2*TSTEPS) ----
  relay_gather(hb[(TSTEPS+1)&1], v1 + XD, go, 2u*TSTEPS, wg, tid, &budget);
  __syncthreads();
  {
    int w = tid >> 6, l6 = tid & 63;
    int k = 256 * w + 4 * l6;
    float4 hv  = *(const float4*)(v1 + XD + k);
    float4 wy4 = *(const float4*)(wyS + k);
    float ys = fmaf(hv.x, wy4.x, fmaf(hv.y, wy4.y, fmaf(hv.z, wy4.z, hv.w * wy4.w)));
    ys += __shfl_xor(ys, 32); ys += __shfl_xor(ys, 16); ys += __shfl_xor(ys, 8);
    ys += __shfl_xor(ys, 4);  ys += __shfl_xor(ys, 2);  ys += __shfl_xor(ys, 1);
    if (l6 == 0) red[8 + w] = ys;
  }
  __syncthreads();
  if (tid == 0) {
    float y = red[8]+red[9]+red[10]+red[11]+red[12]+red[13]+red[14]+red[15] + red[40];
    out[(size_t)(TSTEPS-1) * YD + wg] = y;
  }
  if (tid < 8) out[(size_t)TSTEPS * YD + col0 + tid] = v1[XD + col0 + tid];
}

extern "C" void kernel_launch(void* const* d_in, const int* in_sizes, int n_in,
                              void* d_out, int out_size, void* d_ws, size_t ws_size,
                              hipStream_t stream) {
  const float* x  = (const float*)d_in[0];
  const float* h0 = (const float*)d_in[1];
  const float* Wc = (const float*)d_in[2];
  const float* Wu = (const float*)d_in[3];
  const float* Wr = (const float*)d_in[4];
  const float* bc = (const float*)d_in[5];
  const float* bu = (const float*)d_in[6];
  const float* br = (const float*)d_in[7];
  const float* Wy = (const float*)d_in[8];
  const float* by = (const float*)d_in[9];
  float* out = (float*)d_out;
  unsigned* wsu = (unsigned*)d_ws;

  // >64 KB dynamic LDS on gfx950 (160 KB/CU). Idempotent; capture-safe.
  hipFuncSetAttribute((const void*)gru_persistent,
                      hipFuncAttributeMaxDynamicSharedMemorySize, LDS_BYTES);
  hipMemsetAsync(d_ws, 0, GO_BYTES, stream);                         // go epochs = 0
  hipMemsetAsync((char*)d_ws + GO_BYTES, 0x7F, BUF_BYTES, stream);   // arm sentinels
  gru_persistent<<<dim3(NWG), dim3(NT), LDS_BYTES, stream>>>(
      x, h0, Wc, Wu, Wr, bc, bu, br, Wy, by, out, wsu);
}

// Round 7
// 23875.706 us; speedup vs baseline: 1.1682x; 1.1682x over previous
//
#include <hip/hip_runtime.h>
#include <hip/hip_bf16.h>

#define TSTEPS 4096
#define XD 256
#define HD 2048
#define YD 256
#define KD 2304   // XD + HD
#define NWG 256
#define NT 512

// ---- LDS layout (bytes) ----
#define WU_OFF 0
#define WR_OFF (8*KD*2)            // 36864
#define WC_OFF (16*KD*2)           // 73728
#define WY_OFF (24*KD*2)           // 110592
#define V1_OFF (WY_OFF + HD*4)     // 118784  v1 = [x_t | h_{t-1}]
#define V2_OFF (V1_OFF + KD*4)     // 128000  v2 = [x_t | r]
#define RED_OFF (V2_OFF + KD*4)    // 137216  red: u[8], yp[8], bu[8], br[8], bc[8], by
#define LDS_BYTES (RED_OFF + 256)  // 137472

// ---- workspace (u32 indices; flag/go lines 128B apart) ----
// Monotone epoch flags — no sentinels, no re-arm, no buffer arming needed.
#define HFLAGS_U32 0               // hflags[w] at w*32   (256 lines, 32 KB)
#define RFLAGS_U32 8192            // rflags[w] at ...    (32 KB)
#define HGO_U32    16384           // 8 lines (1 KB)
#define RGO_U32    16640           // 8 lines (1 KB)
#define WS_ZERO_BYTES 67584        // all flags+go zeroed per launch
#define HB0_OFF 67584              // h exchange buffers (8 KB each)
#define HB1_OFF 75776
#define RB0_OFF 83968              // r exchange buffers
#define RB1_OFF 92160

__device__ __forceinline__ float bflo(unsigned u){ return __uint_as_float(u << 16); }
__device__ __forceinline__ float bfhi(unsigned u){ return __uint_as_float(u & 0xffff0000u); }
__device__ __forceinline__ unsigned short f2bf(float f){
  unsigned b = __float_as_uint(f);
  b += 0x7fffu + ((b >> 16) & 1u);   // RTNE (inputs finite)
  return (unsigned short)(b >> 16);
}
__device__ __forceinline__ float sigmoidf_(float x){ return 1.0f / (1.0f + __expf(-x)); }

__device__ __forceinline__ void gst32f(float* p, float v){
  __hip_atomic_store(p, v, __ATOMIC_RELAXED, __HIP_MEMORY_SCOPE_AGENT);
}
__device__ __forceinline__ void flagst(unsigned* p, unsigned v){
  __hip_atomic_store(p, v, __ATOMIC_RELAXED, __HIP_MEMORY_SCOPE_AGENT);
}
__device__ __forceinline__ void spinflag(const unsigned* p, unsigned epoch, long* budget){
  while (__hip_atomic_load(p, __ATOMIC_RELAXED, __HIP_MEMORY_SCOPE_AGENT) < epoch) {
    if (--(*budget) < 0) break;     // anti-hang: proceed rather than deadlock
    __builtin_amdgcn_s_sleep(1);
  }
}

// AGENT-scope coalesced 16B load (sc1 only = LLC-serviced; R4's sc0+sc1 was
// system scope -> HBM RTT). Issued ONLY after relay certification — no
// speculative read storms (R3/R5/R6 lesson: extra LLC readers in the produce
// window delay the producers' own stores).
__device__ __forceinline__ float4 cohload16(const float4* p){
  float4 r;
  asm volatile("global_load_dwordx4 %0, %1, off sc1\n\t"
               "s_waitcnt vmcnt(0)"
               : "=v"(r) : "v"(p) : "memory");
  return r;
}

// R2-style relay barrier: producers stored flag[wg]=epoch (after a vmcnt-
// draining __syncthreads, so data is certified at LLC first). WG0: 255
// threads poll 255 distinct flag lines; then 8 go lines broadcast the epoch;
// other WGs: tid0 polls its go line (<=32 pollers/line). Minimal-reader
// property is the whole point.
__device__ __forceinline__ void relay_wait(unsigned* flags, unsigned* go,
                                           unsigned epoch, int wg, int tid, long* budget){
  if (wg == 0) {
    if (tid >= 1 && tid < NWG) spinflag(flags + tid*32, epoch, budget);
    __syncthreads();
    if (tid < 8) flagst(go + tid*32, epoch);
  } else {
    if (tid == 0) spinflag(go + (wg & 7)*32, epoch, budget);
    __syncthreads();
  }
}

// Unrolled K-chunk of a column dot: v[4*(lane+STRIDE*i)] dot bf16 weights.
template<int I0, int I1, int STRIDE>
__device__ __forceinline__ void dotacc(const float* v, const unsigned short* wcol,
                                       int lane, float4& acc){
  #pragma unroll
  for (int i = I0; i < I1; ++i) {
    int k = 4 * (lane + STRIDE * i);
    float4 vv = *(const float4*)(v + k);
    uint2  wq = *(const uint2*)(wcol + k);
    acc.x = fmaf(vv.x, bflo(wq.x), acc.x);
    acc.y = fmaf(vv.y, bfhi(wq.x), acc.y);
    acc.z = fmaf(vv.z, bflo(wq.y), acc.z);
    acc.w = fmaf(vv.w, bfhi(wq.y), acc.w);
  }
}

extern "C" __global__ void __launch_bounds__(NT)
gru_persistent(const float* __restrict__ x,  const float* __restrict__ h0,
               const float* __restrict__ Wc, const float* __restrict__ Wu,
               const float* __restrict__ Wr, const float* __restrict__ bc,
               const float* __restrict__ bu, const float* __restrict__ br,
               const float* __restrict__ Wy, const float* __restrict__ by,
               float* __restrict__ out, unsigned* wsu)
{
  extern __shared__ char smem[];
  unsigned short* wuS = (unsigned short*)(smem + WU_OFF);
  unsigned short* wrS = (unsigned short*)(smem + WR_OFF);
  unsigned short* wcS = (unsigned short*)(smem + WC_OFF);
  float* wyS = (float*)(smem + WY_OFF);
  float* v1  = (float*)(smem + V1_OFF);
  float* v2  = (float*)(smem + V2_OFF);
  float* red = (float*)(smem + RED_OFF);

  unsigned* hflags = wsu + HFLAGS_U32;
  unsigned* rflags = wsu + RFLAGS_U32;
  unsigned* hgo    = wsu + HGO_U32;
  unsigned* rgo    = wsu + RGO_U32;
  float* hb[2] = { (float*)((char*)wsu + HB0_OFF), (float*)((char*)wsu + HB1_OFF) };
  float* rb[2] = { (float*)((char*)wsu + RB0_OFF), (float*)((char*)wsu + RB1_OFF) };

  const int wg = blockIdx.x, tid = threadIdx.x;
  const int col0 = 8 * wg;

  // ---- one-time weight staging: WG j owns gate cols [8j,8j+8), y col j ----
  for (int idx = tid; idx < 8*KD; idx += NT) {
    int c = idx & 7, k = idx >> 3;
    size_t g = (size_t)k * HD + col0 + c;   // W is [KD, 2048] row-major
    wuS[c*KD + k] = f2bf(Wu[g]);
    wrS[c*KD + k] = f2bf(Wr[g]);
    wcS[c*KD + k] = f2bf(Wc[g]);
  }
  for (int k = tid; k < HD; k += NT) wyS[k] = Wy[(size_t)k * YD + wg];
  if (tid < 8) {
    red[16+tid] = bu[col0+tid];
    red[24+tid] = br[col0+tid];
    red[32+tid] = bc[col0+tid];
  }
  if (tid == 0) red[40] = by[wg];
  __syncthreads();

  long budget = 20000000;   // spin cap, then bail (no hang)

  // x prefetch pipeline: xpref holds x_t at the top of each step.
  float4 xpref = make_float4(0.f, 0.f, 0.f, 0.f);
  if (tid < XD/4) xpref = ((const float4*)x)[tid];

  const int hw = tid >> 5, l = tid & 31, c = hw & 7;   // phase-1 mapping
  const int w  = tid >> 6, l6 = tid & 63;              // phase-2 / y mapping
  const unsigned short* wcol = ((hw < 8) ? wuS : wrS) + c * KD;
  const unsigned short* ccol = wcS + w * KD;

  for (int t = 0; t < TSTEPS; ++t) {
    // x_t into LDS from registers (no HBM on the critical path)
    if (tid < XD/4) {
      ((float4*)v1)[tid] = xpref;
      ((float4*)v2)[tid] = xpref;
    }
    __syncthreads();

    // phase-1 x-part (K=0..255): no h dependency -> overlaps the h relay legs
    float4 a1 = make_float4(0.f, 0.f, 0.f, 0.f);
    dotacc<0, 2, 32>(v1, wcol, l, a1);

    // ---- h_{t-1} exchange ----
    if (t == 0) {
      ((float4*)(v1 + XD))[tid] = ((const float4*)h0)[tid];
      __syncthreads();
    } else {
      relay_wait(hflags, hgo, (unsigned)t, wg, tid, &budget);
      float4 hv = cohload16((const float4*)hb[(t+1)&1] + tid);  // certified
      ((float4*)(v1 + XD))[tid] = hv;
      __syncthreads();
    }

    // ---- phase 1: Lu (half-waves 0-7), Lr (8-15), h-part K=256..2303 ----
    dotacc<2, 18, 32>(v1, wcol, l, a1);
    {
      float s = (a1.x + a1.y) + (a1.z + a1.w);
      s += __shfl_xor(s, 16); s += __shfl_xor(s, 8); s += __shfl_xor(s, 4);
      s += __shfl_xor(s, 2);  s += __shfl_xor(s, 1);
      if (l == 0) {
        if (hw < 8) red[c] = sigmoidf_(s + red[16+c]);                              // u gate
        else gst32f(rb[t&1] + col0 + c, sigmoidf_(s + red[24+c]) * v1[XD+col0+c]);  // r*h
      }
    }
    __syncthreads();                                   // drain r stores (vmcnt 0)
    if (tid == 0) flagst(rflags + wg*32, (unsigned)(t+1));

    // hidden window (overlaps r relay legs): y[t-1] partials + x_{t+1} prefetch
    {
      int k = 256 * w + 4 * l6;
      float4 hv  = *(const float4*)(v1 + XD + k);
      float4 wy4 = *(const float4*)(wyS + k);
      float ys = fmaf(hv.x, wy4.x, fmaf(hv.y, wy4.y, fmaf(hv.z, wy4.z, hv.w * wy4.w)));
      ys += __shfl_xor(ys, 32); ys += __shfl_xor(ys, 16); ys += __shfl_xor(ys, 8);
      ys += __shfl_xor(ys, 4);  ys += __shfl_xor(ys, 2);  ys += __shfl_xor(ys, 1);
      if (l6 == 0) red[8 + w] = ys;
    }
    if (tid < XD/4 && t + 1 < TSTEPS)
      xpref = ((const float4*)(x + (size_t)(t+1) * XD))[tid];

    // ---- r_t exchange ----
    relay_wait(rflags, rgo, (unsigned)(t+1), wg, tid, &budget);
    {
      float4 rv = cohload16((const float4*)rb[t&1] + tid);   // certified
      ((float4*)(v2 + XD))[tid] = rv;
    }
    __syncthreads();
    // y[t-1] store: fire-and-forget, latency hidden under phase 2
    if (tid == 0 && t > 0) {
      float y = red[8]+red[9]+red[10]+red[11]+red[12]+red[13]+red[14]+red[15] + red[40];
      out[(size_t)(t-1) * YD + wg] = y;
    }

    // ---- phase 2: candidate (wave w -> col w), full K ----
    {
      float4 a2 = make_float4(0.f, 0.f, 0.f, 0.f);
      dotacc<0, 9, 64>(v2, ccol, l6, a2);
      float s = (a2.x + a2.y) + (a2.z + a2.w);
      s += __shfl_xor(s, 32); s += __shfl_xor(s, 16); s += __shfl_xor(s, 8);
      s += __shfl_xor(s, 4);  s += __shfl_xor(s, 2);  s += __shfl_xor(s, 1);
      if (l6 == 0) {
        float cc = tanhf(s + red[32 + w]);
        float u  = red[w];
        float hp = v1[XD + col0 + w];
        gst32f(hb[t&1] + col0 + w, cc * u + hp * (1.0f - u));  // h_t slice
      }
    }
    __syncthreads();                                   // drain h stores
    if (tid == 0) flagst(hflags + wg*32, (unsigned)(t+1));
  }

  // ---- epilogue: y[T-1] and h_fin ----
  relay_wait(hflags, hgo, (unsigned)TSTEPS, wg, tid, &budget);
  {
    float4 hv = cohload16((const float4*)hb[(TSTEPS-1)&1] + tid);
    ((float4*)(v1 + XD))[tid] = hv;
  }
  __syncthreads();
  {
    int k = 256 * w + 4 * l6;
    float4 hv  = *(const float4*)(v1 + XD + k);
    float4 wy4 = *(const float4*)(wyS + k);
    float ys = fmaf(hv.x, wy4.x, fmaf(hv.y, wy4.y, fmaf(hv.z, wy4.z, hv.w * wy4.w)));
    ys += __shfl_xor(ys, 32); ys += __shfl_xor(ys, 16); ys += __shfl_xor(ys, 8);
    ys += __shfl_xor(ys, 4);  ys += __shfl_xor(ys, 2);  ys += __shfl_xor(ys, 1);
    if (l6 == 0) red[8 + w] = ys;
  }
  __syncthreads();
  if (tid == 0) {
    float y = red[8]+red[9]+red[10]+red[11]+red[12]+red[13]+red[14]+red[15] + red[40];
    out[(size_t)(TSTEPS-1) * YD + wg] = y;
  }
  if (tid < 8) out[(size_t)TSTEPS * YD + col0 + tid] = v1[XD + col0 + tid];
}

extern "C" void kernel_launch(void* const* d_in, const int* in_sizes, int n_in,
                              void* d_out, int out_size, void* d_ws, size_t ws_size,
                              hipStream_t stream) {
  const float* x  = (const float*)d_in[0];
  const float* h0 = (const float*)d_in[1];
  const float* Wc = (const float*)d_in[2];
  const float* Wu = (const float*)d_in[3];
  const float* Wr = (const float*)d_in[4];
  const float* bc = (const float*)d_in[5];
  const float* bu = (const float*)d_in[6];
  const float* br = (const float*)d_in[7];
  const float* Wy = (const float*)d_in[8];
  const float* by = (const float*)d_in[9];
  float* out = (float*)d_out;
  unsigned* wsu = (unsigned*)d_ws;

  // >64 KB dynamic LDS on gfx950 (160 KB/CU). Idempotent; capture-safe.
  hipFuncSetAttribute((const void*)gru_persistent,
                      hipFuncAttributeMaxDynamicSharedMemorySize, LDS_BYTES);
  hipMemsetAsync(d_ws, 0, WS_ZERO_BYTES, stream);   // zero all flag/go epochs
  gru_persistent<<<dim3(NWG), dim3(NT), LDS_BYTES, stream>>>(
      x, h0, Wc, Wu, Wr, bc, bu, br, Wy, by, out, wsu);
}